// Round 10
// baseline (235.141 us; speedup 1.0000x reference)
//
#include <hip/hip_runtime.h>
#include <hip/hip_cooperative_groups.h>

namespace cg = cooperative_groups;

typedef __attribute__((ext_vector_type(8))) short short8;
typedef __attribute__((ext_vector_type(8))) _Float16 half8;
typedef __attribute__((ext_vector_type(4))) float floatx4;
typedef unsigned short u16;

#define MFMA_BF16(a,b,c) __builtin_amdgcn_mfma_f32_16x16x32_bf16((a),(b),(c),0,0,0)
#define MFMA_F16(a,b,c)  __builtin_amdgcn_mfma_f32_16x16x32_f16((a),(b),(c),0,0,0)

__device__ __forceinline__ u16 f2bf(float f) {
    union { float f; unsigned u; } v; v.f = f;
    unsigned r = (v.u + 0x7fffu + ((v.u >> 16) & 1u)) >> 16;
    return (u16)r;
}
__device__ __forceinline__ float bf2f(u16 h) {
    union { unsigned u; float f; } v; v.u = ((unsigned)h) << 16;
    return v.f;
}
__device__ __forceinline__ u16 f2h(float f) {
    union { _Float16 h; u16 u; } v; v.h = (_Float16)f;
    return v.u;
}

__device__ __forceinline__ void gll16(const u16* g, u16* l) {
    __builtin_amdgcn_global_load_lds(
        (const __attribute__((address_space(1))) void*)g,
        (__attribute__((address_space(3))) void*)l, 16, 0, 0);
}

// ---------------------------------------------------------------------------
// Fat f16 GEMM core: (AR*16) x (BR*16) output tile, K=512, BK=32, dbuf,
// one barrier/step, swizzled LDS. AR+BR = 24 chunks (24 KB/buffer).
// 8 waves, wave tile 64x64 (msub/nsub given by caller), acc[4][4].
// ---------------------------------------------------------------------------
template<int AR, int BR>
__device__ __forceinline__ void gemm_fat(
    const u16* __restrict__ A, const u16* __restrict__ B,
    u16* smem, floatx4 acc[4][4],
    int lane, int wave, int msub, int nsub, int srow, int koff, int pA)
{
    const int l16 = lane & 15;
    const int BUF = (AR + BR) * 512;

    auto stage = [&](int k0, u16* L) {
        #pragma unroll
        for (int i = 0; i < (AR + BR) / 8; ++i) {
            int idx = wave + i * 8;
            const u16* s = (idx < AR)
                ? A + (idx * 16 + srow) * 512 + k0 + koff
                : B + ((idx - AR) * 16 + srow) * 512 + k0 + koff;
            gll16(s, L + idx * 512);
        }
    };

    stage(0, smem);
    for (int k0 = 0; k0 < 512; k0 += 32) {
        __syncthreads();
        u16* L = smem + ((k0 >> 5) & 1) * BUF;
        if (k0 + 32 < 512)
            stage(k0 + 32, smem + (((k0 >> 5) + 1) & 1) * BUF);

        half8 af[4], bfr[4];
        #pragma unroll
        for (int mt = 0; mt < 4; ++mt)
            af[mt] = *(const half8*)(L + (msub + mt * 16 + l16) * 32 + pA);
        #pragma unroll
        for (int nt = 0; nt < 4; ++nt)
            bfr[nt] = *(const half8*)(L + AR * 512 + (nsub + nt * 16 + l16) * 32 + pA);
        #pragma unroll
        for (int mt = 0; mt < 4; ++mt)
            #pragma unroll
            for (int nt = 0; nt < 4; ++nt)
                acc[mt][nt] = MFMA_F16(af[mt], bfr[nt], acc[mt][nt]);
    }
    __syncthreads();
}

// ---------------------------------------------------------------------------
// mega_kernel: cooperative, grid 256 x 512 threads, 4 phases + 3 grid syncs.
// ---------------------------------------------------------------------------
__global__ __launch_bounds__(512, 1) void mega_kernel(
    const void* __restrict__ x,
    const void* __restrict__ Wq, const void* __restrict__ Wk,
    const void* __restrict__ Wv, const void* __restrict__ Wo,
    u16* __restrict__ xT, u16* __restrict__ Wqk,
    u16* __restrict__ Wv16, u16* __restrict__ Wo16,
    u16* __restrict__ qT, u16* __restrict__ kT,
    u16* __restrict__ vbuf, u16* __restrict__ yT,
    void* __restrict__ out)
{
    __shared__ __align__(16) u16 smem[25600];   // 50 KB
    const int tid  = threadIdx.x;
    const int bid  = blockIdx.x;
    const int lane = tid & 63;
    const int wave = tid >> 6;                  // 0..7
    const int quad = lane >> 4, l16 = lane & 15;
    const int srow = lane >> 2;
    const int koff = (((lane & 3) - (srow >> 1)) & 3) * 8;
    const int pA   = ((quad + (l16 >> 1)) & 3) * 8;

    // dtype sniff — uniform result in every wave (all read the same 64 vals)
    int isf32;
    {
        u16 u = ((const u16*)x)[2 * lane];
        int e = (u >> 7) & 0xFF;
        unsigned long long m = __ballot(e >= 96 && e <= 140);
        isf32 = (__popcll(m) >= 40) ? 0 : 1;
    }

    cg::grid_group gg = cg::this_grid();

    //======================= phase 0: prep =======================
    {
        // weights -> f16 (Wq/Wk stacked into Wqk[1024][512])
        #pragma unroll
        for (int m = 0; m < 4; ++m) {
            const void* src = (m == 0) ? Wq : (m == 1) ? Wk : (m == 2) ? Wv : Wo;
            u16* dst = (m == 0) ? Wqk : (m == 1) ? (Wqk + 262144)
                     : (m == 2) ? Wv16 : Wo16;
            #pragma unroll
            for (int j = 0; j < 2; ++j) {
                int i = bid * 1024 + j * 512 + tid;
                float v = isf32 ? ((const float*)src)[i] : bf2f(((const u16*)src)[i]);
                dst[i] = f2h(v);
            }
        }
        // x transpose: 2 tiles/block, two 256-thread halves
        const int half = tid >> 8;
        const int t256 = tid & 255;
        float* tf = (float*)smem + half * 4160;   // 64 x 65
        const int tileIdx = bid * 2 + half;       // 0..511
        const int b   = tileIdx >> 7;
        const int rem = tileIdx & 127;
        const int c0  = (rem >> 4) * 64;
        const int n0  = (rem & 15) * 64;
        const int r = t256 >> 6, col = t256 & 63;
        const size_t base = (size_t)b * 512 * 1024;
        #pragma unroll
        for (int i = 0; i < 16; ++i) {
            int c = i * 4 + r;
            size_t idx = base + (size_t)(c0 + c) * 1024 + n0 + col;
            float v = isf32 ? ((const float*)x)[idx] : bf2f(((const u16*)x)[idx]);
            tf[c * 65 + col] = v;
        }
        __syncthreads();
        #pragma unroll
        for (int i = 0; i < 16; ++i) {
            int n = i * 4 + r;
            xT[((size_t)b * 1024 + n0 + n) * 512 + c0 + col] = f2h(tf[col * 65 + n]);
        }
    }
    gg.sync();

    //======================= phase 1: proj =======================
    if (bid < 192) {
        floatx4 acc[4][4];
        #pragma unroll
        for (int i = 0; i < 4; ++i)
            #pragma unroll
            for (int j = 0; j < 4; ++j) acc[i][j] = (floatx4){0.f, 0.f, 0.f, 0.f};

        if (bid < 128) {
            // q/k: A = xT (256 rows of stacked b,n), B = Wqk (128 of 1024)
            const int m0   = (bid >> 3) * 256;
            const int oblk = (bid & 7) * 128;
            const int msub = (wave & 3) * 64, nsub = (wave >> 2) * 64;
            gemm_fat<16, 8>(xT + (size_t)m0 * 512, Wqk + oblk * 512,
                            smem, acc, lane, wave, msub, nsub, srow, koff, pA);
            #pragma unroll
            for (int mt = 0; mt < 4; ++mt)
                #pragma unroll
                for (int r = 0; r < 4; ++r) {
                    int row = m0 + msub + mt * 16 + quad * 4 + r;
                    int b = row >> 10, n = row & 1023;
                    #pragma unroll
                    for (int nt = 0; nt < 4; ++nt) {
                        int o = oblk + nsub + nt * 16 + l16;
                        float f = acc[mt][nt][r];
                        if (o < 512)
                            qT[((b * 8 + (o >> 6)) * 1024 + n) * 64 + (o & 63)] = f2h(f);
                        else {
                            int ok = o - 512;
                            kT[((b * 8 + (ok >> 6)) * 1024 + n) * 64 + (ok & 63)] = f2h(f);
                        }
                    }
                }
        } else {
            // v: A = Wv (128 rows of o), B = xT (256 rows of stacked b,n)
            const int j2 = bid - 128;             // 0..63
            const int o0  = (j2 >> 4) * 128;
            const int n0v = (j2 & 15) * 256;
            const int msub = (wave & 1) * 64, nsub = (wave >> 1) * 64;
            gemm_fat<8, 16>(Wv16 + o0 * 512, xT + (size_t)n0v * 512,
                            smem, acc, lane, wave, msub, nsub, srow, koff, pA);
            #pragma unroll
            for (int mt = 0; mt < 4; ++mt)
                #pragma unroll
                for (int r = 0; r < 4; ++r) {
                    int o = o0 + msub + mt * 16 + quad * 4 + r;
                    #pragma unroll
                    for (int nt = 0; nt < 4; ++nt) {
                        int col = n0v + nsub + nt * 16 + l16;
                        int b = col >> 10, n = col & 1023;
                        vbuf[b * 524288 + o * 1024 + n] = f2bf(acc[mt][nt][r]);
                    }
                }
        }
    }
    gg.sync();

    //======================= phase 2: attn =======================
    {
        const int head = bid & 31;
        const int i0 = (bid >> 5) * 128 + wave * 16;
        const int b = head >> 3, h = head & 7;
        const u16* qp = qT + head * 65536;
        const u16* kp = kT + head * 65536;
        const u16* vb = vbuf + b * 524288 + h * 65536;

        const int qoff = (i0 + l16) * 64 + quad * 8;
        half8 aq0 = *(const half8*)(qp + qoff);
        half8 aq1 = *(const half8*)(qp + qoff + 32);

        float lacc[4];
        floatx4 oacc[4];
        #pragma unroll
        for (int r = 0; r < 4; ++r) lacc[r] = 0.f;
        #pragma unroll
        for (int dt = 0; dt < 4; ++dt) oacc[dt] = (floatx4){0.f, 0.f, 0.f, 0.f};

        u16* myp = smem + 16384 + wave * 1152;
        const float L2E = 1.44269504f;
        const float C2  = 69.2493619f;   // 48 * log2(e)

        auto stage_kv = [&](int j0, u16* L) {
            #pragma unroll
            for (int i = 0; i < 2; ++i) {
                int c = wave + i * 8;
                const u16* s;
                if (c < 8) {
                    int kc = c >> 2, r0 = (c & 3) * 16;
                    s = kp + (j0 + r0 + srow) * 64 + kc * 32 + koff;
                } else {
                    int c8 = c - 8, js = c8 >> 2, r0 = (c8 & 3) * 16;
                    s = vb + (r0 + srow) * 1024 + j0 + js * 32 + koff;
                }
                gll16(s, L + c * 512);
            }
        };

        stage_kv(0, smem);
        for (int j0 = 0; j0 < 1024; j0 += 64) {
            __syncthreads();
            u16* L = smem + ((j0 >> 6) & 1) * 8192;
            if (j0 + 64 < 1024)
                stage_kv(j0 + 64, smem + (((j0 >> 6) + 1) & 1) * 8192);

            floatx4 sc[4];
            #pragma unroll
            for (int jt = 0; jt < 4; ++jt) {
                int off = jt * 512 + l16 * 32 + pA;
                half8 kh0 = *(const half8*)(L + off);
                half8 kh1 = *(const half8*)(L + 2048 + off);
                floatx4 s = {0.f, 0.f, 0.f, 0.f};
                s = MFMA_F16(aq0, kh0, s);
                s = MFMA_F16(aq1, kh1, s);
                sc[jt] = s;
            }

            #pragma unroll
            for (int jt = 0; jt < 4; ++jt)
                #pragma unroll
                for (int r = 0; r < 4; ++r) {
                    float p = __builtin_amdgcn_exp2f(sc[jt][r] * L2E - C2);
                    lacc[r] += p;
                    myp[(quad * 4 + r) * 72 + jt * 16 + l16] = f2bf(p);
                }
            __asm__ volatile("s_waitcnt lgkmcnt(0)" ::: "memory");
            short8 pa0 = *(const short8*)(myp + l16 * 72 + quad * 8);
            short8 pa1 = *(const short8*)(myp + l16 * 72 + 32 + quad * 8);

            #pragma unroll
            for (int dt = 0; dt < 4; ++dt) {
                int off = dt * 512 + l16 * 32 + pA;
                short8 bv0 = *(const short8*)(L + 4096 + off);
                short8 bv1 = *(const short8*)(L + 4096 + 2048 + off);
                oacc[dt] = MFMA_BF16(pa0, bv0, oacc[dt]);
                oacc[dt] = MFMA_BF16(pa1, bv1, oacc[dt]);
            }
        }

        float linv[4];
        #pragma unroll
        for (int r = 0; r < 4; ++r) {
            float l = lacc[r];
            l += __shfl_xor(l, 1);
            l += __shfl_xor(l, 2);
            l += __shfl_xor(l, 4);
            l += __shfl_xor(l, 8);
            linv[r] = 1.0f / l;
        }
        __syncthreads();
        #pragma unroll
        for (int dt = 0; dt < 4; ++dt)
            #pragma unroll
            for (int r = 0; r < 4; ++r) {
                int c = h * 64 + dt * 16 + l16;
                int n = i0 + quad * 4 + r;
                yT[((size_t)b * 1024 + n) * 512 + c] = f2h(oacc[dt][r] * linv[r]);
            }
    }
    gg.sync();

    //======================= phase 3: out =======================
    if (bid < 64) {
        floatx4 acc[4][4];
        #pragma unroll
        for (int i = 0; i < 4; ++i)
            #pragma unroll
            for (int j = 0; j < 4; ++j) acc[i][j] = (floatx4){0.f, 0.f, 0.f, 0.f};

        const int o0 = (bid >> 4) * 128;
        const int n0 = (bid & 15) * 256;
        const int msub = (wave & 1) * 64, nsub = (wave >> 1) * 64;
        gemm_fat<8, 16>(Wo16 + o0 * 512, yT + (size_t)n0 * 512,
                        smem, acc, lane, wave, msub, nsub, srow, koff, pA);
        #pragma unroll
        for (int mt = 0; mt < 4; ++mt)
            #pragma unroll
            for (int r = 0; r < 4; ++r) {
                int o = o0 + msub + mt * 16 + quad * 4 + r;
                #pragma unroll
                for (int nt = 0; nt < 4; ++nt) {
                    int col = n0 + nsub + nt * 16 + l16;
                    int b = col >> 10, n = col & 1023;
                    size_t di = (size_t)b * 524288 + o * 1024 + n;
                    if (isf32) ((float*)out)[di] = acc[mt][nt][r];
                    else       ((u16*)out)[di] = f2bf(acc[mt][nt][r]);
                }
            }
    }
}

extern "C" void kernel_launch(void* const* d_in, const int* in_sizes, int n_in,
                              void* d_out, int out_size, void* d_ws, size_t ws_size,
                              hipStream_t stream)
{
    const void* x  = d_in[0];
    const void* Wq = d_in[1];
    const void* Wk = d_in[2];
    const void* Wv = d_in[3];
    const void* Wo = d_in[4];

    char* p = (char*)d_ws;
    u16* xT   = (u16*)p; p += 2097152ull * 2;
    u16* Wqk  = (u16*)p; p += 524288ull * 2;
    u16* Wv16 = (u16*)p; p += 262144ull * 2;
    u16* Wo16 = (u16*)p; p += 262144ull * 2;
    u16* qT   = (u16*)p; p += 2097152ull * 2;
    u16* kT   = (u16*)p; p += 2097152ull * 2;
    u16* vbuf = (u16*)p; p += 2097152ull * 2;
    u16* yT   = (u16*)p; p += 2097152ull * 2;
    void* outp = d_out;

    void* args[] = {
        (void*)&x, (void*)&Wq, (void*)&Wk, (void*)&Wv, (void*)&Wo,
        (void*)&xT, (void*)&Wqk, (void*)&Wv16, (void*)&Wo16,
        (void*)&qT, (void*)&kT, (void*)&vbuf, (void*)&yT, (void*)&outp
    };
    hipLaunchCooperativeKernel((const void*)mega_kernel,
                               dim3(256), dim3(512), args, 0, stream);
}

// Round 11
// 117.696 us; speedup vs baseline: 1.9979x; 1.9979x over previous
//
#include <hip/hip_runtime.h>

typedef __attribute__((ext_vector_type(8))) short short8;
typedef __attribute__((ext_vector_type(8))) _Float16 half8;
typedef __attribute__((ext_vector_type(4))) float floatx4;
typedef __attribute__((ext_vector_type(4))) float floatv4;
typedef __attribute__((ext_vector_type(4))) short short4v;
typedef __attribute__((ext_vector_type(4))) unsigned short ushort4v;
typedef unsigned short u16;

#define MFMA_BF16(a,b,c) __builtin_amdgcn_mfma_f32_16x16x32_bf16((a),(b),(c),0,0,0)
#define MFMA_F16(a,b,c)  __builtin_amdgcn_mfma_f32_16x16x32_f16((a),(b),(c),0,0,0)

__device__ __forceinline__ u16 f2bf(float f) {
    union { float f; unsigned u; } v; v.f = f;
    unsigned r = (v.u + 0x7fffu + ((v.u >> 16) & 1u)) >> 16;
    return (u16)r;
}
__device__ __forceinline__ float bf2f(u16 h) {
    union { unsigned u; float f; } v; v.u = ((unsigned)h) << 16;
    return v.f;
}
__device__ __forceinline__ u16 f2h(float f) {
    union { _Float16 h; u16 u; } v; v.h = (_Float16)f;
    return v.u;
}

__device__ __forceinline__ void gll16(const u16* g, u16* l) {
    __builtin_amdgcn_global_load_lds(
        (const __attribute__((address_space(1))) void*)g,
        (__attribute__((address_space(3))) void*)l, 16, 0, 0);
}

// ---------------------------------------------------------------------------
// prep_kernel: sniff + x -> xT f16 (transpose) + W -> f16. Vectorized 4x.
// blocks 0..511: xpose 64x64 tiles; 512..575: weight conversion.
// ---------------------------------------------------------------------------
__global__ __launch_bounds__(256) void prep_kernel(
    const void* __restrict__ x,
    const void* __restrict__ Wq, const void* __restrict__ Wk,
    const void* __restrict__ Wv, const void* __restrict__ Wo,
    u16* __restrict__ xT,
    u16* __restrict__ Wqh, u16* __restrict__ Wkh,
    u16* __restrict__ Wvh, u16* __restrict__ Woh,
    int* __restrict__ flag)
{
    __shared__ float tile[64][65];
    __shared__ int sflag;
    const int tid = threadIdx.x;

    if (tid < 64) {
        u16 u = ((const u16*)x)[2 * tid];
        int e = (u >> 7) & 0xFF;
        unsigned long long m = __ballot(e >= 96 && e <= 140);
        if (tid == 0) sflag = (__popcll(m) >= 40) ? 0 : 1;
    }
    __syncthreads();
    const int isf32 = sflag;
    const int bid = blockIdx.x;
    if (bid == 0 && tid == 0) *flag = isf32;

    if (bid < 512) {
        const int b = bid >> 7, rem = bid & 127;
        const int c0 = (rem >> 4) * 64, n0 = (rem & 15) * 64;
        const int cr = tid >> 4;          // 0..15
        const int n4 = (tid & 15) * 4;
        const size_t base = (size_t)b * 512 * 1024;
        #pragma unroll
        for (int i = 0; i < 4; ++i) {
            int c = i * 16 + cr;
            size_t idx = base + (size_t)(c0 + c) * 1024 + n0 + n4;
            float v0, v1, v2, v3;
            if (isf32) {
                floatv4 v = *(const floatv4*)((const float*)x + idx);
                v0 = v[0]; v1 = v[1]; v2 = v[2]; v3 = v[3];
            } else {
                ushort4v u = *(const ushort4v*)((const u16*)x + idx);
                v0 = bf2f(u[0]); v1 = bf2f(u[1]); v2 = bf2f(u[2]); v3 = bf2f(u[3]);
            }
            tile[c][n4 + 0] = v0; tile[c][n4 + 1] = v1;
            tile[c][n4 + 2] = v2; tile[c][n4 + 3] = v3;
        }
        __syncthreads();
        const int nr = tid >> 4;
        const int c4 = (tid & 15) * 4;
        #pragma unroll
        for (int i = 0; i < 4; ++i) {
            int n = i * 16 + nr;
            short4v o;
            o[0] = (short)f2h(tile[c4 + 0][n]);
            o[1] = (short)f2h(tile[c4 + 1][n]);
            o[2] = (short)f2h(tile[c4 + 2][n]);
            o[3] = (short)f2h(tile[c4 + 3][n]);
            *(short4v*)(xT + ((size_t)b * 1024 + n0 + n) * 512 + c0 + c4) = o;
        }
    } else {
        const int b2 = bid - 512;   // 0..63
        #pragma unroll
        for (int m = 0; m < 4; ++m) {
            const void* src = (m == 0) ? Wq : (m == 1) ? Wk : (m == 2) ? Wv : Wo;
            u16* dst = (m == 0) ? Wqh : (m == 1) ? Wkh : (m == 2) ? Wvh : Woh;
            #pragma unroll
            for (int j = 0; j < 4; ++j) {
                int i = b2 * 4096 + j * 1024 + tid * 4;
                short4v o;
                if (isf32) {
                    floatv4 v = *(const floatv4*)((const float*)src + i);
                    o[0] = (short)f2h(v[0]); o[1] = (short)f2h(v[1]);
                    o[2] = (short)f2h(v[2]); o[3] = (short)f2h(v[3]);
                } else {
                    ushort4v u = *(const ushort4v*)((const u16*)src + i);
                    o[0] = (short)f2h(bf2f(u[0])); o[1] = (short)f2h(bf2f(u[1]));
                    o[2] = (short)f2h(bf2f(u[2])); o[3] = (short)f2h(bf2f(u[3]));
                }
                *(short4v*)(dst + i) = o;
            }
        }
    }
}

// ---------------------------------------------------------------------------
// single-term f16 GEMM core: 64(M) x 128(N), K=512, BK=32, double-buffered,
// one barrier/step, swizzled LDS. Chunks/buffer: A 0-3, B 4-11 (12 KB).
// ---------------------------------------------------------------------------
__device__ __forceinline__ void stage_1t(
    const u16* __restrict__ A, const u16* __restrict__ B,
    u16* L, int k0, int wave, int srow, int koff)
{
    #pragma unroll
    for (int i = 0; i < 3; ++i) {
        int idx = wave + i * 4;
        const u16* s;
        if (idx < 4) s = A + (idx * 16 + srow) * 512 + k0 + koff;
        else         s = B + ((idx - 4) * 16 + srow) * 512 + k0 + koff;
        gll16(s, L + idx * 512);
    }
}

__device__ __forceinline__ void gemm_1t(
    const u16* __restrict__ A, const u16* __restrict__ B,
    u16* lds, floatx4 acc[2][4], int lane, int wave)
{
    const int quad = lane >> 4, l16 = lane & 15;
    const int msub = (wave & 1) * 32, nsub = (wave >> 1) * 64;
    const int srow = lane >> 2;
    const int koff = (((lane & 3) - (srow >> 1)) & 3) * 8;
    const int pA = ((quad + (l16 >> 1)) & 3) * 8;

    stage_1t(A, B, lds, 0, wave, srow, koff);
    for (int k0 = 0; k0 < 512; k0 += 32) {
        __syncthreads();
        u16* L = lds + ((k0 >> 5) & 1) * 6144;
        if (k0 + 32 < 512)
            stage_1t(A, B, lds + (((k0 >> 5) + 1) & 1) * 6144,
                     k0 + 32, wave, srow, koff);

        half8 ah[2], bh[4];
        #pragma unroll
        for (int mt = 0; mt < 2; ++mt)
            ah[mt] = *(const half8*)(L + (msub + mt * 16 + l16) * 32 + pA);
        #pragma unroll
        for (int nt = 0; nt < 4; ++nt)
            bh[nt] = *(const half8*)(L + 2048 + (nsub + nt * 16 + l16) * 32 + pA);
        #pragma unroll
        for (int mt = 0; mt < 2; ++mt)
            #pragma unroll
            for (int nt = 0; nt < 4; ++nt)
                acc[mt][nt] = MFMA_F16(ah[mt], bh[nt], acc[mt][nt]);
    }
}

// ---------------------------------------------------------------------------
// proj_kernel: 768 blocks, all single-term f16.
// ---------------------------------------------------------------------------
__global__ __launch_bounds__(256) void proj_kernel(
    const u16* __restrict__ xT,
    const u16* __restrict__ Wqh, const u16* __restrict__ Wkh,
    const u16* __restrict__ Wvh,
    u16* __restrict__ qT, u16* __restrict__ kT,
    u16* __restrict__ vbuf)
{
    __shared__ u16 lds[12288];
    const int lane = threadIdx.x & 63;
    const int wave = threadIdx.x >> 6;
    const int quad = lane >> 4, l16 = lane & 15;
    const int idx = blockIdx.x;
    const int msub = (wave & 1) * 32, nsub = (wave >> 1) * 64;

    floatx4 acc[2][4];
    #pragma unroll
    for (int i = 0; i < 2; ++i)
        #pragma unroll
        for (int j = 0; j < 4; ++j) acc[i][j] = (floatx4){0.f, 0.f, 0.f, 0.f};

    if (idx < 512) {
        const int w = idx >> 8;
        const int rem = idx & 255;
        const int m0 = (rem >> 2) * 64;        // stacked (b,n)
        const int oblk = (rem & 3) * 128;      // o
        gemm_1t(xT + (size_t)m0 * 512, ((w == 0) ? Wqh : Wkh) + oblk * 512,
                lds, acc, lane, wave);

        u16* dst = (w == 0) ? qT : kT;
        #pragma unroll
        for (int mt = 0; mt < 2; ++mt)
            #pragma unroll
            for (int r = 0; r < 4; ++r) {
                int row = m0 + msub + mt * 16 + quad * 4 + r;
                int b = row >> 10, n = row & 1023;
                #pragma unroll
                for (int nt = 0; nt < 4; ++nt) {
                    int o = oblk + nsub + nt * 16 + l16;
                    int head = b * 8 + (o >> 6);
                    int dd = o & 63;
                    dst[(head * 1024 + n) * 64 + dd] = f2h(acc[mt][nt][r]);
                }
            }
    } else {
        const int rem = idx - 512;
        const int m0 = (rem >> 5) * 64;        // o
        const int nblk = (rem & 31) * 128;     // stacked (b,n)
        gemm_1t(Wvh + m0 * 512, xT + (size_t)nblk * 512, lds, acc, lane, wave);

        #pragma unroll
        for (int mt = 0; mt < 2; ++mt)
            #pragma unroll
            for (int r = 0; r < 4; ++r) {
                int o = m0 + msub + mt * 16 + quad * 4 + r;
                #pragma unroll
                for (int nt = 0; nt < 4; ++nt) {
                    int col = nblk + nsub + nt * 16 + l16;
                    int b = col >> 10, n = col & 1023;
                    vbuf[b * 524288 + o * 1024 + n] = f2bf(acc[mt][nt][r]);
                }
            }
    }
}

// ---------------------------------------------------------------------------
// attn_kernel: 512 threads (8 waves = 128 queries), grid (head=32, qtile=8).
// S^T formulation: S^T = K.Q^T (A=K from LDS, B=q regs), P^T B-fragments
// built via register shuffles (no P LDS round-trip), O^T = V^T.P^T.
// K(f16)/V(bf16) double-buffered; LDS = 32 KB -> 4 blocks/CU.
// ---------------------------------------------------------------------------
__global__ __launch_bounds__(512) void attn_kernel(
    const u16* __restrict__ qT, const u16* __restrict__ kT,
    const u16* __restrict__ vbuf,
    u16* __restrict__ yT)
{
    __shared__ u16 lds[16384];   // 2 x 8192 shorts
    const int lane = threadIdx.x & 63;
    const int wave = threadIdx.x >> 6;      // 0..7
    const int quad = lane >> 4, l16 = lane & 15;
    const int head = blockIdx.x;
    const int i0 = blockIdx.y * 128 + wave * 16;
    const int b = head >> 3, h = head & 7;
    const u16* qp = qT + head * 65536;
    const u16* kp = kT + head * 65536;
    const u16* vb = vbuf + b * 524288 + h * 65536;
    const int srow = lane >> 2;
    const int koff = (((lane & 3) - (srow >> 1)) & 3) * 8;
    const int pA = ((quad + (l16 >> 1)) & 3) * 8;

    const int qoff = (i0 + l16) * 64 + quad * 8;
    half8 aq0 = *(const half8*)(qp + qoff);
    half8 aq1 = *(const half8*)(qp + qoff + 32);

    float lsum = 0.f;
    floatx4 oacc[4];
    #pragma unroll
    for (int dt = 0; dt < 4; ++dt) oacc[dt] = (floatx4){0.f, 0.f, 0.f, 0.f};

    const float L2E = 1.44269504f;
    const float C2  = 69.2493619f;   // 48 * log2(e)

    auto stage_kv = [&](int j0, u16* L) {
        #pragma unroll
        for (int i = 0; i < 2; ++i) {
            int c = wave + i * 8;
            const u16* s;
            if (c < 8) {
                int kc = c >> 2, r0 = (c & 3) * 16;
                s = kp + (j0 + r0 + srow) * 64 + kc * 32 + koff;
            } else {
                int c8 = c - 8, js = c8 >> 2, r0 = (c8 & 3) * 16;
                s = vb + (r0 + srow) * 1024 + j0 + js * 32 + koff;
            }
            gll16(s, L + c * 512);
        }
    };

    stage_kv(0, lds);

    const int srcA = (quad & 1) * 32 + l16;
    const int srcB = srcA + 16;
    const bool hi = (quad >> 1) != 0;

    for (int j0 = 0; j0 < 1024; j0 += 64) {
        __syncthreads();
        u16* L = lds + ((j0 >> 6) & 1) * 8192;
        if (j0 + 64 < 1024)
            stage_kv(j0 + 64, lds + (((j0 >> 6) + 1) & 1) * 8192);

        // S^T tiles: st[jt] row j=jt*16+quad*4+r, col i=l16. Then exp+pack bf16.
        unsigned pk[4][2];
        #pragma unroll
        for (int jt = 0; jt < 4; ++jt) {
            int off = jt * 512 + l16 * 32 + pA;
            half8 kh0 = *(const half8*)(L + off);
            half8 kh1 = *(const half8*)(L + 2048 + off);
            floatx4 s = {0.f, 0.f, 0.f, 0.f};
            s = MFMA_F16(kh0, aq0, s);
            s = MFMA_F16(kh1, aq1, s);
            float p0 = __builtin_amdgcn_exp2f(s[0] * L2E - C2);
            float p1 = __builtin_amdgcn_exp2f(s[1] * L2E - C2);
            float p2 = __builtin_amdgcn_exp2f(s[2] * L2E - C2);
            float p3 = __builtin_amdgcn_exp2f(s[3] * L2E - C2);
            lsum += (p0 + p1) + (p2 + p3);
            pk[jt][0] = (unsigned)f2bf(p0) | ((unsigned)f2bf(p1) << 16);
            pk[jt][1] = (unsigned)f2bf(p2) | ((unsigned)f2bf(p3) << 16);
        }

        // PV: O^T += V^T . P^T ; P^T B-frag via shuffles.
        #pragma unroll
        for (int jc = 0; jc < 2; ++jc) {
            unsigned a0 = (unsigned)__shfl((int)pk[jc * 2][0], srcA);
            unsigned b0 = (unsigned)__shfl((int)pk[jc * 2 + 1][0], srcA);
            unsigned a1 = (unsigned)__shfl((int)pk[jc * 2][1], srcA);
            unsigned b1 = (unsigned)__shfl((int)pk[jc * 2 + 1][1], srcA);
            unsigned a2 = (unsigned)__shfl((int)pk[jc * 2][0], srcB);
            unsigned b2 = (unsigned)__shfl((int)pk[jc * 2 + 1][0], srcB);
            unsigned a3 = (unsigned)__shfl((int)pk[jc * 2][1], srcB);
            unsigned b3 = (unsigned)__shfl((int)pk[jc * 2 + 1][1], srcB);
            union { unsigned u[4]; short8 s8; } pu;
            pu.u[0] = hi ? b0 : a0;
            pu.u[1] = hi ? b1 : a1;
            pu.u[2] = hi ? b2 : a2;
            pu.u[3] = hi ? b3 : a3;
            short8 pfrag = pu.s8;
            #pragma unroll
            for (int dt = 0; dt < 4; ++dt) {
                int off = dt * 512 + l16 * 32 + pA;
                short8 vv = *(const short8*)(L + 4096 + jc * 2048 + off);
                oacc[dt] = MFMA_BF16(vv, pfrag, oacc[dt]);
            }
        }
    }

    lsum += __shfl_xor(lsum, 16);
    lsum += __shfl_xor(lsum, 32);
    const float linv = 1.0f / lsum;

    u16* yrow = yT + ((size_t)b * 1024 + i0 + l16) * 512 + h * 64;
    #pragma unroll
    for (int dt = 0; dt < 4; ++dt) {
        short4v o;
        #pragma unroll
        for (int r = 0; r < 4; ++r) o[r] = (short)f2h(oacc[dt][r] * linv);
        *(short4v*)(yrow + dt * 16 + quad * 4) = o;
    }
}

// ---------------------------------------------------------------------------
// out_kernel: Wo(f16) @ yT(f16), 64(o) x 128(b,n) tiles via gemm_1t.
// ---------------------------------------------------------------------------
__global__ __launch_bounds__(256) void out_kernel(
    const u16* __restrict__ Woh, const u16* __restrict__ yT,
    void* __restrict__ out, const int* __restrict__ flag)
{
    __shared__ u16 lds[12288];
    const int isf32 = *flag;
    const int lane = threadIdx.x & 63;
    const int wave = threadIdx.x >> 6;
    const int quad = lane >> 4, l16 = lane & 15;
    const int nblk = blockIdx.x * 128;   // stacked (b,n)
    const int oblk = blockIdx.y * 64;    // o

    floatx4 acc[2][4];
    #pragma unroll
    for (int i = 0; i < 2; ++i)
        #pragma unroll
        for (int j = 0; j < 4; ++j) acc[i][j] = (floatx4){0.f, 0.f, 0.f, 0.f};

    gemm_1t(Woh + oblk * 512, yT + (size_t)nblk * 512, lds, acc, lane, wave);

    const int msub = (wave & 1) * 32, nsub = (wave >> 1) * 64;
    #pragma unroll
    for (int mt = 0; mt < 2; ++mt)
        #pragma unroll
        for (int r = 0; r < 4; ++r) {
            int o = oblk + msub + mt * 16 + quad * 4 + r;
            #pragma unroll
            for (int nt = 0; nt < 4; ++nt) {
                int col = nblk + nsub + nt * 16 + l16;
                int b = col >> 10, n = col & 1023;
                size_t di = (size_t)b * 524288 + o * 1024 + n;
                if (isf32) ((float*)out)[di] = acc[mt][nt][r];
                else       ((u16*)out)[di] = f2bf(acc[mt][nt][r]);
            }
        }
}

extern "C" void kernel_launch(void* const* d_in, const int* in_sizes, int n_in,
                              void* d_out, int out_size, void* d_ws, size_t ws_size,
                              hipStream_t stream)
{
    const void* x  = d_in[0];
    const void* Wq = d_in[1];
    const void* Wk = d_in[2];
    const void* Wv = d_in[3];
    const void* Wo = d_in[4];

    const int NX = 4 * 512 * 1024;
    const int NW = 512 * 512;

    char* p = (char*)d_ws;
    int* flag = (int*)p; p += 64;
    u16* xT   = (u16*)p; p += (size_t)NX * 2;
    u16* Wqh  = (u16*)p; p += (size_t)NW * 2;
    u16* Wkh  = (u16*)p; p += (size_t)NW * 2;
    u16* Wvh  = (u16*)p; p += (size_t)NW * 2;
    u16* Woh  = (u16*)p; p += (size_t)NW * 2;
    u16* qT   = (u16*)p; p += (size_t)NX * 2;
    u16* kT   = (u16*)p; p += (size_t)NX * 2;
    u16* vbuf = (u16*)p; p += (size_t)NX * 2;
    u16* ybuf = (u16*)p; p += (size_t)NX * 2;

    prep_kernel<<<576, 256, 0, stream>>>(
        x, Wq, Wk, Wv, Wo, xT, Wqh, Wkh, Wvh, Woh, flag);
    proj_kernel<<<768, 256, 0, stream>>>(
        xT, Wqh, Wkh, Wvh, qT, kT, vbuf);
    attn_kernel<<<dim3(32, 8), 512, 0, stream>>>(
        qT, kT, vbuf, ybuf);
    out_kernel<<<dim3(32, 8), 256, 0, stream>>>(
        Woh, ybuf, d_out, flag);
}